// Round 10
// baseline (5545.227 us; speedup 1.0000x reference)
//
#include <hip/hip_runtime.h>

#define N_ROWS 65536
#define DIM 64
#define KCB 1024
#define Q_ELEMS 4194304   // 64*64*32*32
#define RPB 256           // rows per block (64 lanes x 4 rows/thread)
#define KQ 256            // codewords per wave (K-quarter)
#define TILE 32           // codewords per LDS tile
#define NTILES 8          // KQ / TILE

// ws layout (bytes): [0,4096) float wn2[1024]; [4096,5120) float partial[256]

// Bit-exact replica of numpy's pairwise sum of squares for 64 fp32 values.
__device__ __forceinline__ float np_pairwise_sumsq64(const float* v) {
#pragma clang fp contract(off)
    float r[8];
#pragma unroll
    for (int j = 0; j < 8; ++j) r[j] = v[j] * v[j];
#pragma unroll
    for (int i = 8; i < 64; i += 8) {
#pragma unroll
        for (int j = 0; j < 8; ++j) {
            float s = v[i + j] * v[i + j];
            r[j] = r[j] + s;
        }
    }
    return ((r[0] + r[1]) + (r[2] + r[3])) + ((r[4] + r[5]) + (r[6] + r[7]));
}

__global__ __launch_bounds__(64) void wnorm_kernel(const float* __restrict__ w,
                                                   float* __restrict__ wn2) {
    __shared__ float tile[64][65];
    const int t = threadIdx.x;
    const size_t base = (size_t)blockIdx.x * 64 * DIM;
#pragma unroll 4
    for (int i = 0; i < 64; ++i)
        tile[i][t] = w[base + (size_t)i * DIM + t];   // coalesced
    __syncthreads();
    float v[DIM];
#pragma unroll
    for (int d = 0; d < DIM; ++d) v[d] = tile[t][d];  // stride 65 -> conflict-free
    wn2[blockIdx.x * 64 + t] = np_pairwise_sumsq64(v);
}

// R10: 4 rows/thread. DS broadcast (16 x ds_read_b128 ~= 192 cyc) per codeword
// now amortizes over 256 dots/wave (was 128). NO __launch_bounds__ on purpose:
// empirically (R5/R6/R7) any bound w sets VGPR budget ~256/w and spills the
// 256-float x live set to scratch (R6: 1.7 GB of scratch traffic). Boundless
// -> ~300+ VGPR, 1 wave/SIMD, no spill (m08: clean through 450).
__global__ void vq_kernel(const float* __restrict__ x,
                          const float* __restrict__ w,
                          const float* __restrict__ wn2,
                          float* __restrict__ out,
                          float* __restrict__ partial) {
    __shared__ float wtile[4][TILE * DIM];   // 32 KB; recycled for reductions

    const int t = threadIdx.x;
    const int lane = t & 63;
    const int wv = t >> 6;                   // 4 waves, each owns a K-quarter
    const int rowbase = blockIdx.x * RPB;

    // 4 x rows -> 256 VGPRs
    float xr[4][DIM];
#pragma unroll
    for (int s = 0; s < 4; ++s) {
        const float4* xv = (const float4*)(x + (size_t)(rowbase + s * 64 + lane) * DIM);
#pragma unroll
        for (int i = 0; i < 16; ++i) {
            float4 a = xv[i];
            xr[s][4 * i + 0] = a.x; xr[s][4 * i + 1] = a.y;
            xr[s][4 * i + 2] = a.z; xr[s][4 * i + 3] = a.w;
        }
    }
    float S[4];
#pragma unroll
    for (int s = 0; s < 4; ++s) S[s] = np_pairwise_sumsq64(xr[s]);

    const int kbase = wv * KQ;               // this wave's K-quarter
    float best[4] = {3.4e38f, 3.4e38f, 3.4e38f, 3.4e38f};
    int bi[4] = {kbase, kbase, kbase, kbase};

    for (int tile = 0; tile < NTILES; ++tile) {
        // stage 32 codewords (8 KB) into this wave's private LDS region
        const float* gsrc = w + (size_t)(kbase + tile * TILE) * DIM;
        float* ldst = &wtile[wv][0];
#pragma unroll
        for (int j = 0; j < 8; ++j) {
            float4 v = *(const float4*)(gsrc + j * 256 + lane * 4);
            *(float4*)(ldst + j * 256 + lane * 4) = v;
        }
        // same-wave LDS RAW -> compiler-inserted lgkmcnt; no barrier needed

        for (int c = 0; c < TILE; c += 2) {
            const float* w0 = ldst + c * DIM;
            float a0[4] = {0.f, 0.f, 0.f, 0.f};   // dot(row s, cw c)
            float a1[4] = {0.f, 0.f, 0.f, 0.f};   // dot(row s, cw c+1)
#pragma unroll
            for (int d = 0; d < DIM; d += 4) {
                float4 u0 = *(const float4*)(w0 + d);
                float4 u1 = *(const float4*)(w0 + DIM + d);
#pragma unroll
                for (int s = 0; s < 4; ++s) {
                    float p0 = xr[s][d], p1 = xr[s][d + 1];
                    float p2 = xr[s][d + 2], p3 = xr[s][d + 3];
                    a0[s] = __builtin_fmaf(p0, u0.x, a0[s]);
                    a0[s] = __builtin_fmaf(p1, u0.y, a0[s]);
                    a0[s] = __builtin_fmaf(p2, u0.z, a0[s]);
                    a0[s] = __builtin_fmaf(p3, u0.w, a0[s]);
                    a1[s] = __builtin_fmaf(p0, u1.x, a1[s]);
                    a1[s] = __builtin_fmaf(p1, u1.y, a1[s]);
                    a1[s] = __builtin_fmaf(p2, u1.z, a1[s]);
                    a1[s] = __builtin_fmaf(p3, u1.w, a1[s]);
                }
            }
            const int k = kbase + tile * TILE + c;
            const float wnA = wn2[k], wnB = wn2[k + 1];
#pragma unroll
            for (int s = 0; s < 4; ++s) {
                // fl(fl(S+wn2)-2a): 2a exact, one rounding -> bit-exact replica
                float d0 = (S[s] + wnA) - 2.0f * a0[s];
                float d1 = (S[s] + wnB) - 2.0f * a1[s];
                if (d0 < best[s]) { best[s] = d0; bi[s] = k; }
                if (d1 < best[s]) { best[s] = d1; bi[s] = k + 1; }
            }
        }
    }

    // recycle wtile: cross-quarter argmin + loss reduction
    __syncthreads();
    float* cbd = (float*)&wtile[0][0];                    // [4][256]
    int*   cbk = (int*)((char*)&wtile[0][0] + 4096);      // [4][256]
    float* red = (float*)((char*)&wtile[0][0] + 8192);    // [4]
#pragma unroll
    for (int s = 0; s < 4; ++s) {
        cbd[wv * 256 + s * 64 + lane] = best[s];
        cbk[wv * 256 + s * 64 + lane] = bi[s];
    }
    __syncthreads();

    // thread t handles row rowbase + t; since t = wv*64+lane, that row is
    // exactly this thread's slot-wv row -> its x is xr[wv]. All 256 threads
    // participate.
    float bd = cbd[0 * 256 + t]; int bk = cbk[0 * 256 + t];
#pragma unroll
    for (int q = 1; q < 4; ++q) {   // ascending q + strict < == numpy argmin
        float dq = cbd[q * 256 + t]; int kq = cbk[q * 256 + t];
        if (dq < bd) { bd = dq; bk = kq; }
    }
    float xcur[DIM];
    if (wv == 0) {
#pragma unroll
        for (int d = 0; d < DIM; ++d) xcur[d] = xr[0][d];
    } else if (wv == 1) {
#pragma unroll
        for (int d = 0; d < DIM; ++d) xcur[d] = xr[1][d];
    } else if (wv == 2) {
#pragma unroll
        for (int d = 0; d < DIM; ++d) xcur[d] = xr[2][d];
    } else {
#pragma unroll
        for (int d = 0; d < DIM; ++d) xcur[d] = xr[3][d];
    }
    const int n = rowbase + t;
    const int b = n >> 10;               // H*W = 1024
    const int hw = n & 1023;
    float* outq = out + 1 + (size_t)b * 65536 + hw;
    const float4* wr4 = (const float4*)(w + (size_t)bk * DIM);
    float lsum = 0.f;
#pragma unroll
    for (int i = 0; i < 16; ++i) {
        float4 u = wr4[i];
        float d0 = u.x - xcur[4 * i + 0];
        float d1 = u.y - xcur[4 * i + 1];
        float d2 = u.z - xcur[4 * i + 2];
        float d3 = u.w - xcur[4 * i + 3];
        lsum += d0 * d0; lsum += d1 * d1; lsum += d2 * d2; lsum += d3 * d3;
        outq[(size_t)(4 * i + 0) * 1024] = xcur[4 * i + 0] + d0;
        outq[(size_t)(4 * i + 1) * 1024] = xcur[4 * i + 1] + d1;
        outq[(size_t)(4 * i + 2) * 1024] = xcur[4 * i + 2] + d2;
        outq[(size_t)(4 * i + 3) * 1024] = xcur[4 * i + 3] + d3;
    }
    out[1 + Q_ELEMS + n] = (float)bk;

#pragma unroll
    for (int off = 32; off > 0; off >>= 1) lsum += __shfl_down(lsum, off, 64);
    if (lane == 0) red[wv] = lsum;
    __syncthreads();
    if (t == 0) partial[blockIdx.x] = (red[0] + red[1]) + (red[2] + red[3]);
}

__global__ void finish_kernel(const float* __restrict__ partial, float* __restrict__ out) {
    float v = partial[threadIdx.x];   // 256 partials, 256 threads
#pragma unroll
    for (int off = 32; off > 0; off >>= 1) v += __shfl_down(v, off, 64);
    __shared__ float red[4];
    const int lane = threadIdx.x & 63;
    const int wv = threadIdx.x >> 6;
    if (lane == 0) red[wv] = v;
    __syncthreads();
    if (threadIdx.x == 0) {
        float total = (red[0] + red[1]) + (red[2] + red[3]);
        out[0] = total * (2.0f / (float)(N_ROWS * DIM));
    }
}

extern "C" void kernel_launch(void* const* d_in, const int* in_sizes, int n_in,
                              void* d_out, int out_size, void* d_ws, size_t ws_size,
                              hipStream_t stream) {
    const float* x = (const float*)d_in[0];
    const float* w = (const float*)d_in[1];
    float* out = (float*)d_out;

    char* ws = (char*)d_ws;
    float* wn2 = (float*)(ws + 0);
    float* partial = (float*)(ws + 4096);

    wnorm_kernel<<<KCB / 64, 64, 0, stream>>>(w, wn2);
    vq_kernel<<<N_ROWS / RPB, 256, 0, stream>>>(x, w, wn2, out, partial);
    finish_kernel<<<1, 256, 0, stream>>>(partial, out);
}